// Round 1
// baseline (61.899 us; speedup 1.0000x reference)
//
#include <hip/hip_runtime.h>
#include <cstdint>

// ---------------- problem constants ----------------
static constexpr int RPI    = 256;   // ROIS_PER_IMAGE
static constexpr int MAXPOS = 64;    // round(256*0.25)
static constexpr int MAX_GT = 256;   // LDS capacity for gt boxes (M=200)

// ---------------- workspace layout (bytes) ----------------
static constexpr int    MAX_BLK   = 2048;                      // supports N up to 524288
static constexpr int    MAX_N     = 262144;
static constexpr size_t WS_TOTALS = 0;                         // 2 ints: total_pos, total_neg
static constexpr size_t WS_SLOT   = 64;                        // RPI ints
static constexpr size_t WS_BLKPOS = WS_SLOT + RPI * 4;
static constexpr size_t WS_BLKNEG = WS_BLKPOS + MAX_BLK * 4;
static constexpr size_t WS_POSPRF = WS_BLKNEG + MAX_BLK * 4;
static constexpr size_t WS_NEGPRF = WS_POSPRF + MAX_BLK * 4;
static constexpr size_t WS_BESTGT = WS_NEGPRF + MAX_BLK * 4;   // int16 per ROI
static constexpr size_t WS_KEY    = WS_BESTGT + (size_t)MAX_N * 2; // uint8 per ROI

// ---------------- kernel 1: IoU + classification + per-block counts ----------------
__global__ __launch_bounds__(256) void iou_kernel(
    const float* __restrict__ rois, const float* __restrict__ gts,
    int N, int M,
    uint8_t* __restrict__ key, int16_t* __restrict__ bestgt,
    int* __restrict__ blkPos, int* __restrict__ blkNeg)
{
#pragma clang fp contract(off)
    __shared__ float4 sgt[MAX_GT];
    __shared__ float  sarea[MAX_GT];
    __shared__ int    wcnt[8];

    int tid = threadIdx.x;
    for (int j = tid; j < M; j += 256) {
        float4 g = ((const float4*)gts)[j];
        sgt[j]   = g;
        sarea[j] = (g.z - g.x) * (g.w - g.y);
    }
    __syncthreads();

    int i = blockIdx.x * 256 + tid;
    int k = 2;        // 0=pos, 1=neg, 2=other
    int bidx = 0;
    if (i < N) {
        float4 b = ((const float4*)rois)[i];
        float areaA = (b.z - b.x) * (b.w - b.y);
        float best = -1.0f;
        for (int j = 0; j < M; ++j) {
            float4 g = sgt[j];
            float iy1 = fmaxf(b.x, g.x);
            float ix1 = fmaxf(b.y, g.y);
            float iy2 = fminf(b.z, g.z);
            float ix2 = fminf(b.w, g.w);
            float ih  = fmaxf(iy2 - iy1, 0.0f);
            float iw  = fmaxf(ix2 - ix1, 0.0f);
            float inter = ih * iw;
            float iou = 0.0f;
            if (inter > 0.0f) {                       // 0/x == +0 exactly, so skip is exact
                float uni = (areaA + sarea[j]) - inter;
                iou = inter / (uni + 1e-7f);          // IEEE f32 divide, matches numpy
            }
            if (iou > best) { best = iou; bidx = j; } // strict > == argmax first-occurrence
        }
        key[i]    = (uint8_t)((best > 0.5f) ? 0 : ((best < 0.5f && best > 0.1f) ? 1 : 2));
        bestgt[i] = (int16_t)bidx;
        k = (best > 0.5f) ? 0 : ((best < 0.5f && best > 0.1f) ? 1 : 2);
    }

    unsigned long long mp = __ballot(k == 0);
    unsigned long long mn = __ballot(k == 1);
    int lane = tid & 63, w = tid >> 6;
    if (lane == 0) { wcnt[w] = __popcll(mp); wcnt[4 + w] = __popcll(mn); }
    __syncthreads();
    if (tid == 0) {
        blkPos[blockIdx.x] = wcnt[0] + wcnt[1] + wcnt[2] + wcnt[3];
        blkNeg[blockIdx.x] = wcnt[4] + wcnt[5] + wcnt[6] + wcnt[7];
    }
}

// ---------------- kernel 2: scan per-block counts, totals, slot init ----------------
__global__ __launch_bounds__(1024) void scan_kernel(
    const int* __restrict__ blkPos, const int* __restrict__ blkNeg,
    int* __restrict__ posPref, int* __restrict__ negPref,
    int* __restrict__ totals, int* __restrict__ slot, int nblk)
{
    __shared__ int sp[1024], sn[1024];
    int tid = threadIdx.x;
    int carryP = 0, carryN = 0;
    for (int base = 0; base < nblk; base += 1024) {
        int t  = base + tid;
        int vp = (t < nblk) ? blkPos[t] : 0;
        int vn = (t < nblk) ? blkNeg[t] : 0;
        sp[tid] = vp; sn[tid] = vn;
        __syncthreads();
        for (int off = 1; off < 1024; off <<= 1) {
            int xp = (tid >= off) ? sp[tid - off] : 0;
            int xn = (tid >= off) ? sn[tid - off] : 0;
            __syncthreads();
            sp[tid] += xp; sn[tid] += xn;
            __syncthreads();
        }
        if (t < nblk) {
            posPref[t] = carryP + sp[tid] - vp;   // exclusive prefix
            negPref[t] = carryN + sn[tid] - vn;
        }
        carryP += sp[1023];
        carryN += sn[1023];
        __syncthreads();
    }
    if (tid == 0) {
        int tp  = carryP < MAXPOS ? carryP : MAXPOS;
        int rem = RPI - tp;
        int tn  = carryN < rem ? carryN : rem;
        totals[0] = tp; totals[1] = tn;
    }
    if (tid < RPI) slot[tid] = -1;   // ws is poisoned/stale: must rewrite every launch
}

// ---------------- kernel 3: first-k selection into slots ----------------
__global__ __launch_bounds__(256) void select_kernel(
    const uint8_t* __restrict__ key, const int* __restrict__ posPref,
    const int* __restrict__ negPref, const int* __restrict__ totals,
    int* __restrict__ slot, int N)
{
    __shared__ int wc[8];
    int tp = totals[0], tn = totals[1];
    int bpp = posPref[blockIdx.x], bnp = negPref[blockIdx.x];
    if (bpp >= tp && bnp >= tn) return;   // block-uniform early exit

    int tid = threadIdx.x;
    int i   = blockIdx.x * 256 + tid;
    int k   = (i < N) ? (int)key[i] : 2;

    unsigned long long mp = __ballot(k == 0);
    unsigned long long mn = __ballot(k == 1);
    int lane = tid & 63, w = tid >> 6;
    if (lane == 0) { wc[w] = __popcll(mp); wc[4 + w] = __popcll(mn); }
    __syncthreads();

    unsigned long long lt = (1ull << lane) - 1ull;
    if (k == 0) {
        int off = bpp;
        for (int x = 0; x < w; ++x) off += wc[x];
        int r = off + __popcll(mp & lt);
        if (r < tp) slot[r] = i;
    } else if (k == 1) {
        int off = bnp;
        for (int x = 0; x < w; ++x) off += wc[4 + x];
        int r = off + __popcll(mn & lt);
        if (r < tn) slot[tp + r] = i;
    }
}

// ---------------- kernel 4: epilogue — deltas + one-hot, writes ALL outputs ----------------
__global__ __launch_bounds__(128) void emit_kernel(
    const float* __restrict__ rois, const float* __restrict__ gts,
    const int* __restrict__ labels, const int* __restrict__ slot,
    const int* __restrict__ totals, const int16_t* __restrict__ bestgt,
    float* __restrict__ outD, float* __restrict__ outH)
{
#pragma clang fp contract(off)
    int r   = blockIdx.x;
    int roi = slot[r];
    int tp  = totals[0];
    bool valid = roi >= 0;
    bool ispos = valid && (r < tp);

    float d0 = 0.f, d1 = 0.f, d2 = 0.f, d3 = 0.f;
    int lab = 0;
    if (ispos) {
        int g     = (int)bestgt[roi];
        float4 b  = ((const float4*)rois)[roi];
        float4 gb = ((const float4*)gts)[g];
        lab = labels[g];
        float bh  = b.z - b.x,  bw  = b.w - b.y;
        float bcy = b.x + 0.5f * bh, bcx = b.y + 0.5f * bw;
        float gh  = gb.z - gb.x, gw  = gb.w - gb.y;
        float gcy = gb.x + 0.5f * gh, gcx = gb.y + 0.5f * gw;
        float bhs = (bh == 0.f) ? 1.f : bh;
        float bws = (bw == 0.f) ? 1.f : bw;
        float ghs = (gh <= 0.f) ? 1.f : gh;
        float gws = (gw <= 0.f) ? 1.f : gw;
        float dy = (gh == 0.f) ? 0.f : (gcy - bcy) / bhs;
        float dx = (gw == 0.f) ? 0.f : (gcx - bcx) / bws;
        float dh = (gh == 0.f) ? 0.f : logf(ghs / bhs);
        float dw = (gw == 0.f) ? 0.f : logf(gws / bws);
        d0 = dy / 0.1f; d1 = dx / 0.1f; d2 = dh / 0.2f; d3 = dw / 0.2f;
    }
    // negatives: valid, lab=0 -> one-hot class 0; pads: all zero
    int t = threadIdx.x;
    if (t < 91) outH[r * 91 + t] = (valid && t == lab) ? 1.0f : 0.0f;
    if (t >= 96 && t < 100) {
        float v = (t == 96) ? d0 : (t == 97) ? d1 : (t == 98) ? d2 : d3;
        outD[r * 4 + (t - 96)] = v;
    }
}

// ---------------- host launcher ----------------
extern "C" void kernel_launch(void* const* d_in, const int* in_sizes, int n_in,
                              void* d_out, int out_size, void* d_ws, size_t ws_size,
                              hipStream_t stream) {
    const float* rois   = (const float*)d_in[1];   // [1,N,4]
    const float* gts    = (const float*)d_in[2];   // [1,M,4]
    const int*   labels = (const int*)  d_in[3];   // [1,M]
    int N = in_sizes[1] / 4;
    int M = in_sizes[2] / 4;

    char* ws = (char*)d_ws;
    int*     totals  = (int*)    (ws + WS_TOTALS);
    int*     slot    = (int*)    (ws + WS_SLOT);
    int*     blkPos  = (int*)    (ws + WS_BLKPOS);
    int*     blkNeg  = (int*)    (ws + WS_BLKNEG);
    int*     posPref = (int*)    (ws + WS_POSPRF);
    int*     negPref = (int*)    (ws + WS_NEGPRF);
    int16_t* bestgt  = (int16_t*)(ws + WS_BESTGT);
    uint8_t* key     = (uint8_t*)(ws + WS_KEY);

    int nblk = (N + 255) / 256;

    iou_kernel<<<nblk, 256, 0, stream>>>(rois, gts, N, M, key, bestgt, blkPos, blkNeg);
    scan_kernel<<<1, 1024, 0, stream>>>(blkPos, blkNeg, posPref, negPref, totals, slot, nblk);
    select_kernel<<<nblk, 256, 0, stream>>>(key, posPref, negPref, totals, slot, N);

    float* outD = (float*)d_out;          // [1,256,4]
    float* outH = outD + RPI * 4;         // [1,256,91]
    emit_kernel<<<RPI, 128, 0, stream>>>(rois, gts, labels, slot, totals, bestgt, outD, outH);
}

// Round 2
// 38.876 us; speedup vs baseline: 1.5922x; 1.5922x over previous
//
#include <hip/hip_runtime.h>
#include <cstdint>

// ---------------- problem constants ----------------
static constexpr int RPI    = 256;   // ROIS_PER_IMAGE
static constexpr int MAXPOS = 64;    // round(256*0.25)
static constexpr int MAX_GT = 256;   // LDS capacity for gt boxes (M=200)

// ---------------- workspace layout (bytes) ----------------
static constexpr int    MAX_BLK   = 2048;                      // supports N up to 524288
static constexpr int    MAX_N     = 262144;
static constexpr size_t WS_TOTALS = 0;                         // 2 ints
static constexpr size_t WS_SLOT   = 64;                        // RPI ints
static constexpr size_t WS_BLKPOS = WS_SLOT + RPI * 4;
static constexpr size_t WS_BLKNEG = WS_BLKPOS + MAX_BLK * 4;
static constexpr size_t WS_POSPRF = WS_BLKNEG + MAX_BLK * 4;
static constexpr size_t WS_NEGPRF = WS_POSPRF + MAX_BLK * 4;
static constexpr size_t WS_BESTGT = WS_NEGPRF + MAX_BLK * 4;   // int16 per ROI
static constexpr size_t WS_KEY    = WS_BESTGT + (size_t)MAX_N * 2; // uint8 per ROI

// ---------------- kernel 1: IoU argmax (rational tracking) + classify + counts ----
// Block = 256 threads = 4 waves. Block owns 256 ROIs; each wave processes ALL
// 256 ROIs (4 per thread) against ITS quarter of the GT list; partial
// (best_inter, best_union', best_j) merged in LDS in segment order.
// Exactness: running best kept as the rational (inter, union'); comparison by
// cross-multiplication; ONE IEEE f32 divide per ROI at the end. fl() is
// monotone, so max_j fl(r_j) == fl(max_j r_j) -> threshold compares bit-exact.
__global__ __launch_bounds__(256) void iou_kernel(
    const float* __restrict__ rois, const float* __restrict__ gts,
    int N, int M,
    uint8_t* __restrict__ key, int16_t* __restrict__ bestgt,
    int* __restrict__ blkPos, int* __restrict__ blkNeg)
{
#pragma clang fp contract(off)
    __shared__ float4  sgt[MAX_GT];
    __shared__ float   sarea[MAX_GT];
    __shared__ float   sbi[4][256];
    __shared__ float   sbu[4][256];
    __shared__ int16_t sbj[4][256];
    __shared__ int     wcnt[8];

    int tid = threadIdx.x;
    for (int j = tid; j < M; j += 256) {
        float4 g = ((const float4*)gts)[j];
        sgt[j]   = g;
        sarea[j] = (g.z - g.x) * (g.w - g.y);   // same op order as reference
    }
    __syncthreads();

    int w    = tid >> 6;          // wave id = GT segment id
    int l    = tid & 63;
    int base = blockIdx.x * 256;
    int seglen = (M + 3) >> 2;
    int j0 = w * seglen;
    int j1 = min(M, j0 + seglen);

    float4 b[4];
    float  areaA[4], bi[4], bu[4];
    int    bj[4];
#pragma unroll
    for (int k = 0; k < 4; ++k) {
        int r = base + k * 64 + l;
        b[k] = (r < N) ? ((const float4*)rois)[r] : make_float4(0.f, 0.f, 0.f, 0.f);
        areaA[k] = (b[k].z - b[k].x) * (b[k].w - b[k].y);
        bi[k] = -1.0f;            // first pair always wins: inter*1 > -1*u'
        bu[k] = 1.0f;
        bj[k] = j0;
    }

    for (int j = j0; j < j1; ++j) {
        float4 g  = sgt[j];       // broadcast read (all lanes same addr)
        float  ab = sarea[j];
#pragma unroll
        for (int k = 0; k < 4; ++k) {
            float iy1 = fmaxf(b[k].x, g.x);
            float ix1 = fmaxf(b[k].y, g.y);
            float iy2 = fminf(b[k].z, g.z);
            float ix2 = fminf(b[k].w, g.w);
            float ih  = fmaxf(iy2 - iy1, 0.0f);
            float iw  = fmaxf(ix2 - ix1, 0.0f);
            float inter = ih * iw;
            float u1 = ((areaA[k] + ab) - inter) + 1e-7f;  // exact ref op order
            bool  s  = (inter * bu[k]) > (bi[k] * u1);     // r_j > r_best
            bi[k] = s ? inter : bi[k];
            bu[k] = s ? u1    : bu[k];
            bj[k] = s ? j     : bj[k];
        }
    }

#pragma unroll
    for (int k = 0; k < 4; ++k) {
        int lr = k * 64 + l;
        sbi[w][lr] = bi[k];
        sbu[w][lr] = bu[k];
        sbj[w][lr] = (int16_t)bj[k];
    }
    __syncthreads();

    // merge the 4 segment partials in segment order (strict > keeps first max)
    float BI = sbi[0][tid], BU = sbu[0][tid];
    int   BJ = (int)sbj[0][tid];
#pragma unroll
    for (int s = 1; s < 4; ++s) {
        float ci = sbi[s][tid], cu = sbu[s][tid];
        bool sel = (ci * BU) > (BI * cu);
        BI = sel ? ci : BI;
        BU = sel ? cu : BU;
        BJ = sel ? (int)sbj[s][tid] : BJ;
    }

    int i  = base + tid;
    int kk = 2;
    if (i < N) {
        float q = BI / BU;        // the ONLY division: IEEE f32, == ref merged
        kk = (q > 0.5f) ? 0 : ((q < 0.5f && q > 0.1f) ? 1 : 2);
        key[i]    = (uint8_t)kk;
        bestgt[i] = (int16_t)BJ;
    }

    unsigned long long mp = __ballot(kk == 0);
    unsigned long long mn = __ballot(kk == 1);
    int lane = tid & 63, wv = tid >> 6;
    if (lane == 0) { wcnt[wv] = __popcll(mp); wcnt[4 + wv] = __popcll(mn); }
    __syncthreads();
    if (tid == 0) {
        blkPos[blockIdx.x] = wcnt[0] + wcnt[1] + wcnt[2] + wcnt[3];
        blkNeg[blockIdx.x] = wcnt[4] + wcnt[5] + wcnt[6] + wcnt[7];
    }
}

// ---------------- kernel 2: scan per-block counts, totals, slot init ----------------
__global__ __launch_bounds__(1024) void scan_kernel(
    const int* __restrict__ blkPos, const int* __restrict__ blkNeg,
    int* __restrict__ posPref, int* __restrict__ negPref,
    int* __restrict__ totals, int* __restrict__ slot, int nblk)
{
    __shared__ int sp[1024], sn[1024];
    int tid = threadIdx.x;
    int carryP = 0, carryN = 0;
    for (int base = 0; base < nblk; base += 1024) {
        int t  = base + tid;
        int vp = (t < nblk) ? blkPos[t] : 0;
        int vn = (t < nblk) ? blkNeg[t] : 0;
        sp[tid] = vp; sn[tid] = vn;
        __syncthreads();
        for (int off = 1; off < 1024; off <<= 1) {
            int xp = (tid >= off) ? sp[tid - off] : 0;
            int xn = (tid >= off) ? sn[tid - off] : 0;
            __syncthreads();
            sp[tid] += xp; sn[tid] += xn;
            __syncthreads();
        }
        if (t < nblk) {
            posPref[t] = carryP + sp[tid] - vp;   // exclusive prefix
            negPref[t] = carryN + sn[tid] - vn;
        }
        carryP += sp[1023];
        carryN += sn[1023];
        __syncthreads();
    }
    if (tid == 0) {
        int tp  = carryP < MAXPOS ? carryP : MAXPOS;
        int rem = RPI - tp;
        int tn  = carryN < rem ? carryN : rem;
        totals[0] = tp; totals[1] = tn;
    }
    if (tid < RPI) slot[tid] = -1;   // ws is poisoned/stale: rewrite every launch
}

// ---------------- kernel 3: first-k selection into slots ----------------
__global__ __launch_bounds__(256) void select_kernel(
    const uint8_t* __restrict__ key, const int* __restrict__ posPref,
    const int* __restrict__ negPref, const int* __restrict__ totals,
    int* __restrict__ slot, int N)
{
    __shared__ int wc[8];
    int tp = totals[0], tn = totals[1];
    int bpp = posPref[blockIdx.x], bnp = negPref[blockIdx.x];
    if (bpp >= tp && bnp >= tn) return;   // block-uniform early exit

    int tid = threadIdx.x;
    int i   = blockIdx.x * 256 + tid;
    int k   = (i < N) ? (int)key[i] : 2;

    unsigned long long mp = __ballot(k == 0);
    unsigned long long mn = __ballot(k == 1);
    int lane = tid & 63, w = tid >> 6;
    if (lane == 0) { wc[w] = __popcll(mp); wc[4 + w] = __popcll(mn); }
    __syncthreads();

    unsigned long long lt = (1ull << lane) - 1ull;
    if (k == 0) {
        int off = bpp;
        for (int x = 0; x < w; ++x) off += wc[x];
        int r = off + __popcll(mp & lt);
        if (r < tp) slot[r] = i;
    } else if (k == 1) {
        int off = bnp;
        for (int x = 0; x < w; ++x) off += wc[4 + x];
        int r = off + __popcll(mn & lt);
        if (r < tn) slot[tp + r] = i;
    }
}

// ---------------- kernel 4: epilogue — deltas + one-hot, writes ALL outputs ----------------
__global__ __launch_bounds__(128) void emit_kernel(
    const float* __restrict__ rois, const float* __restrict__ gts,
    const int* __restrict__ labels, const int* __restrict__ slot,
    const int* __restrict__ totals, const int16_t* __restrict__ bestgt,
    float* __restrict__ outD, float* __restrict__ outH)
{
#pragma clang fp contract(off)
    int r   = blockIdx.x;
    int roi = slot[r];
    int tp  = totals[0];
    bool valid = roi >= 0;
    bool ispos = valid && (r < tp);

    float d0 = 0.f, d1 = 0.f, d2 = 0.f, d3 = 0.f;
    int lab = 0;
    if (ispos) {
        int g     = (int)bestgt[roi];
        float4 b  = ((const float4*)rois)[roi];
        float4 gb = ((const float4*)gts)[g];
        lab = labels[g];
        float bh  = b.z - b.x,  bw  = b.w - b.y;
        float bcy = b.x + 0.5f * bh, bcx = b.y + 0.5f * bw;
        float gh  = gb.z - gb.x, gw  = gb.w - gb.y;
        float gcy = gb.x + 0.5f * gh, gcx = gb.y + 0.5f * gw;
        float bhs = (bh == 0.f) ? 1.f : bh;
        float bws = (bw == 0.f) ? 1.f : bw;
        float ghs = (gh <= 0.f) ? 1.f : gh;
        float gws = (gw <= 0.f) ? 1.f : gw;
        float dy = (gh == 0.f) ? 0.f : (gcy - bcy) / bhs;
        float dx = (gw == 0.f) ? 0.f : (gcx - bcx) / bws;
        float dh = (gh == 0.f) ? 0.f : logf(ghs / bhs);
        float dw = (gw == 0.f) ? 0.f : logf(gws / bws);
        d0 = dy / 0.1f; d1 = dx / 0.1f; d2 = dh / 0.2f; d3 = dw / 0.2f;
    }
    int t = threadIdx.x;
    if (t < 91) outH[r * 91 + t] = (valid && t == lab) ? 1.0f : 0.0f;
    if (t >= 96 && t < 100) {
        float v = (t == 96) ? d0 : (t == 97) ? d1 : (t == 98) ? d2 : d3;
        outD[r * 4 + (t - 96)] = v;
    }
}

// ---------------- host launcher ----------------
extern "C" void kernel_launch(void* const* d_in, const int* in_sizes, int n_in,
                              void* d_out, int out_size, void* d_ws, size_t ws_size,
                              hipStream_t stream) {
    const float* rois   = (const float*)d_in[1];   // [1,N,4]
    const float* gts    = (const float*)d_in[2];   // [1,M,4]
    const int*   labels = (const int*)  d_in[3];   // [1,M]
    int N = in_sizes[1] / 4;
    int M = in_sizes[2] / 4;

    char* ws = (char*)d_ws;
    int*     totals  = (int*)    (ws + WS_TOTALS);
    int*     slot    = (int*)    (ws + WS_SLOT);
    int*     blkPos  = (int*)    (ws + WS_BLKPOS);
    int*     blkNeg  = (int*)    (ws + WS_BLKNEG);
    int*     posPref = (int*)    (ws + WS_POSPRF);
    int*     negPref = (int*)    (ws + WS_NEGPRF);
    int16_t* bestgt  = (int16_t*)(ws + WS_BESTGT);
    uint8_t* key     = (uint8_t*)(ws + WS_KEY);

    int nblk = (N + 255) / 256;

    iou_kernel<<<nblk, 256, 0, stream>>>(rois, gts, N, M, key, bestgt, blkPos, blkNeg);
    scan_kernel<<<1, 1024, 0, stream>>>(blkPos, blkNeg, posPref, negPref, totals, slot, nblk);
    select_kernel<<<nblk, 256, 0, stream>>>(key, posPref, negPref, totals, slot, N);

    float* outD = (float*)d_out;          // [1,256,4]
    float* outH = outD + RPI * 4;         // [1,256,91]
    emit_kernel<<<RPI, 128, 0, stream>>>(rois, gts, labels, slot, totals, bestgt, outD, outH);
}

// Round 3
// 36.960 us; speedup vs baseline: 1.6748x; 1.0519x over previous
//
#include <hip/hip_runtime.h>
#include <cstdint>

// ---------------- problem constants ----------------
static constexpr int RPI    = 256;   // ROIS_PER_IMAGE
static constexpr int MAXPOS = 64;    // round(256*0.25)
static constexpr int MAX_GT = 256;   // LDS capacity for gt boxes (M=200)
static constexpr int MAXG   = 4096;  // max 64-ROI groups (N <= 262144)

// ---------------- workspace layout (bytes) ----------------
static constexpr size_t WS_GRPPOS = 0;
static constexpr size_t WS_GRPNEG = WS_GRPPOS + (size_t)MAXG * 4;
static constexpr size_t WS_BESTGT = WS_GRPNEG + (size_t)MAXG * 4;       // int16 per ROI
static constexpr size_t WS_KEY    = WS_BESTGT + (size_t)262144 * 2;     // uint8 per ROI

// ---------------- kernel 1: IoU argmax + classify + per-64-group counts ----------
// Block = 256 threads = 4 waves; block owns C=128 ROIs (2/lane). Each wave
// processes all 128 ROIs against ITS quarter of the GT list (j-split-4).
// Rational best tracked as (bi, c1) where c1 = I_best + U'_best == S_eps at
// update time:  r_c > r_b  ⟺  I_c*c1_b > bi_b*S_eps_c   (U>0, exact algebra;
// fp product rounding only perturbs near-exact ties). Final merged value q is
// RECOMPUTED in exact reference op order from the winning j, then divided
// once (IEEE f32) -> threshold compares bit-exact given correct argmax.
__global__ __launch_bounds__(256) void iou_kernel(
    const float* __restrict__ rois, const float* __restrict__ gts,
    int N, int M,
    uint8_t* __restrict__ key, int16_t* __restrict__ bestgt,
    int* __restrict__ grpPos, int* __restrict__ grpNeg)
{
#pragma clang fp contract(off)
    __shared__ float4 sgt[MAX_GT];
    __shared__ float  sarea[MAX_GT];
    __shared__ float  sabe[MAX_GT];      // area + 1e-7 (comparator-side)
    __shared__ float  sbi[4][128];
    __shared__ float  sc1[4][128];
    __shared__ short  sbj[4][128];

    int tid = threadIdx.x;
    for (int j = tid; j < M; j += 256) {
        float4 g = ((const float4*)gts)[j];
        sgt[j] = g;
        float a = (g.z - g.x) * (g.w - g.y);   // ref op order
        sarea[j] = a;
        sabe[j]  = a + 1e-7f;
    }
    __syncthreads();

    int w = tid >> 6, l = tid & 63;
    int base = blockIdx.x * 128;
    int r0 = base + l, r1 = base + 64 + l;
    float4 b0 = (r0 < N) ? ((const float4*)rois)[r0] : make_float4(0.f,0.f,0.f,0.f);
    float4 b1 = (r1 < N) ? ((const float4*)rois)[r1] : make_float4(0.f,0.f,0.f,0.f);
    float aA0 = (b0.z - b0.x) * (b0.w - b0.y);
    float aA1 = (b1.z - b1.x) * (b1.w - b1.y);

    int seglen = (M + 3) >> 2;
    int j0 = w * seglen, j1 = min(M, j0 + seglen);

    float bi0 = -1.f, c10 = 0.f;   // init: first j always wins (0 > -S)
    float bi1 = -1.f, c11 = 0.f;
    int   bj0 = j0,   bj1 = j0;
    for (int j = j0; j < j1; ++j) {
        float4 g   = sgt[j];         // broadcast LDS read
        float  abe = sabe[j];
        {   // pair 0
            float iy1 = fmaxf(b0.x, g.x), ix1 = fmaxf(b0.y, g.y);
            float iy2 = fminf(b0.z, g.z), ix2 = fminf(b0.w, g.w);
            float ih  = fmaxf(iy2 - iy1, 0.f), iw = fmaxf(ix2 - ix1, 0.f);
            float inter = ih * iw;
            float S = aA0 + abe;
            bool  s = (inter * c10) > (bi0 * S);
            bi0 = s ? inter : bi0;  c10 = s ? S : c10;  bj0 = s ? j : bj0;
        }
        {   // pair 1
            float iy1 = fmaxf(b1.x, g.x), ix1 = fmaxf(b1.y, g.y);
            float iy2 = fminf(b1.z, g.z), ix2 = fminf(b1.w, g.w);
            float ih  = fmaxf(iy2 - iy1, 0.f), iw = fmaxf(ix2 - ix1, 0.f);
            float inter = ih * iw;
            float S = aA1 + abe;
            bool  s = (inter * c11) > (bi1 * S);
            bi1 = s ? inter : bi1;  c11 = s ? S : c11;  bj1 = s ? j : bj1;
        }
    }
    sbi[w][l]      = bi0;  sc1[w][l]      = c10;  sbj[w][l]      = (short)bj0;
    sbi[w][64 + l] = bi1;  sc1[w][64 + l] = c11;  sbj[w][64 + l] = (short)bj1;
    __syncthreads();

    if (tid < 128) {                 // waves 0,1: one ROI each
        float BI = sbi[0][tid], C1 = sc1[0][tid];
        int   BJ = (int)sbj[0][tid];
#pragma unroll
        for (int s2 = 1; s2 < 4; ++s2) {
            // challenger (ci,cc) vs best (BI,C1): ci*C1 > BI*cc  (exact algebra,
            // the ci*BI terms cancel). Empty/never case impossible (M>=4).
            float ci = sbi[s2][tid], cc = sc1[s2][tid];
            bool sel = (ci * C1) > (BI * cc);
            BI = sel ? ci : BI;  C1 = sel ? cc : C1;
            BJ = sel ? (int)sbj[s2][tid] : BJ;
        }
        float4 bb = (tid < 64) ? b0 : b1;
        float  aa = (tid < 64) ? aA0 : aA1;
        int r = base + tid;
        int kk = 2;
        if (r < N) {
            // exact recompute of merged = iou(r, BJ) in reference op order
            float4 g  = sgt[BJ];
            float  ab = sarea[BJ];
            float iy1 = fmaxf(bb.x, g.x), ix1 = fmaxf(bb.y, g.y);
            float iy2 = fminf(bb.z, g.z), ix2 = fminf(bb.w, g.w);
            float ih  = fmaxf(iy2 - iy1, 0.f), iw = fmaxf(ix2 - ix1, 0.f);
            float inter = ih * iw;
            float u1 = ((aa + ab) - inter) + 1e-7f;
            float q  = inter / u1;             // the ONLY division
            kk = (q > 0.5f) ? 0 : ((q < 0.5f && q > 0.1f) ? 1 : 2);
            key[r]    = (uint8_t)kk;
            bestgt[r] = (int16_t)BJ;
        }
        unsigned long long mp = __ballot(kk == 0);
        unsigned long long mn = __ballot(kk == 1);
        if (l == 0) {
            grpPos[blockIdx.x * 2 + w] = __popcll(mp);
            grpNeg[blockIdx.x * 2 + w] = __popcll(mn);
        }
    }
}

// ---------------- kernel 2: fused scan + select + emit (single block) ------------
__global__ __launch_bounds__(1024) void finish_kernel(
    const float* __restrict__ rois, const float* __restrict__ gts,
    const int* __restrict__ labels,
    const uint8_t* __restrict__ key, const int16_t* __restrict__ bestgt,
    const int* __restrict__ grpPos, const int* __restrict__ grpNeg,
    float* __restrict__ outD, float* __restrict__ outH,
    int N, int ngroups)
{
#pragma clang fp contract(off)
    __shared__ int pp[MAXG], pn[MAXG];   // exclusive prefixes per 64-ROI group
    __shared__ int sp[1024], sn[1024];
    __shared__ int slot[RPI];
    __shared__ int slab[RPI];

    int tid = threadIdx.x;
    // ---- scan: 4 groups/thread, one Hillis pass over 1024 thread-sums ----
    int t4 = tid * 4;
    int vp[4], vn[4];
#pragma unroll
    for (int k = 0; k < 4; ++k) {
        int g = t4 + k;
        vp[k] = (g < ngroups) ? grpPos[g] : 0;
        vn[k] = (g < ngroups) ? grpNeg[g] : 0;
    }
    int sump = vp[0] + vp[1] + vp[2] + vp[3];
    int sumn = vn[0] + vn[1] + vn[2] + vn[3];
    sp[tid] = sump; sn[tid] = sumn;
    __syncthreads();
    for (int off = 1; off < 1024; off <<= 1) {
        int xp = (tid >= off) ? sp[tid - off] : 0;
        int xn = (tid >= off) ? sn[tid - off] : 0;
        __syncthreads();
        sp[tid] += xp; sn[tid] += xn;
        __syncthreads();
    }
    int totP = sp[1023], totN = sn[1023];
    int tp  = totP < MAXPOS ? totP : MAXPOS;
    int rem = RPI - tp;
    int tn  = totN < rem ? totN : rem;
    int exP = sp[tid] - sump, exN = sn[tid] - sumn;
#pragma unroll
    for (int k = 0; k < 4; ++k) {
        pp[t4 + k] = exP; exP += vp[k];
        pn[t4 + k] = exN; exN += vn[k];
    }
    if (tid < RPI) slot[tid] = -1;
    __syncthreads();

    // ---- select: one wave per group, first-k by ballot rank ----
    int wid = tid >> 6, lane = tid & 63;
    for (int g = wid; g < ngroups; g += 16) {
        int gp = pp[g], gn = pn[g];
        if (gp >= tp && gn >= tn) break;     // prefixes monotone -> done
        int i = g * 64 + lane;
        int k = (i < N) ? (int)key[i] : 2;
        unsigned long long mp = __ballot(k == 0);
        unsigned long long mn = __ballot(k == 1);
        unsigned long long lt = (1ull << lane) - 1ull;
        if (k == 0) {
            int rr = gp + __popcll(mp & lt);
            if (rr < tp) slot[rr] = i;
        } else if (k == 1) {
            int rr = gn + __popcll(mn & lt);
            if (rr < tn) slot[tp + rr] = i;
        }
    }
    __syncthreads();

    // ---- emit: deltas + label per row ----
    if (tid < RPI) {
        int  roi   = slot[tid];
        bool valid = roi >= 0;
        bool ispos = valid && (tid < tp);
        float d0 = 0.f, d1 = 0.f, d2 = 0.f, d3 = 0.f;
        int lab = valid ? 0 : -1;            // -1 => all-zero one-hot row
        if (ispos) {
            int g     = (int)bestgt[roi];
            float4 b  = ((const float4*)rois)[roi];
            float4 gb = ((const float4*)gts)[g];
            lab = labels[g];
            float bh  = b.z - b.x,  bw  = b.w - b.y;
            float bcy = b.x + 0.5f * bh, bcx = b.y + 0.5f * bw;
            float gh  = gb.z - gb.x, gw  = gb.w - gb.y;
            float gcy = gb.x + 0.5f * gh, gcx = gb.y + 0.5f * gw;
            float bhs = (bh == 0.f) ? 1.f : bh;
            float bws = (bw == 0.f) ? 1.f : bw;
            float ghs = (gh <= 0.f) ? 1.f : gh;
            float gws = (gw <= 0.f) ? 1.f : gw;
            float dy = (gh == 0.f) ? 0.f : (gcy - bcy) / bhs;
            float dx = (gw == 0.f) ? 0.f : (gcx - bcx) / bws;
            float dh = (gh == 0.f) ? 0.f : logf(ghs / bhs);
            float dw = (gw == 0.f) ? 0.f : logf(gws / bws);
            d0 = dy / 0.1f; d1 = dx / 0.1f; d2 = dh / 0.2f; d3 = dw / 0.2f;
        }
        slab[tid] = lab;
        ((float4*)outD)[tid] = make_float4(d0, d1, d2, d3);
    }
    __syncthreads();

    // ---- one-hot: coalesced over 256*91 ----
    for (int idx = tid; idx < RPI * 91; idx += 1024) {
        int rr = idx / 91;
        int cc = idx - rr * 91;
        outH[idx] = (cc == slab[rr]) ? 1.0f : 0.0f;
    }
}

// ---------------- host launcher ----------------
extern "C" void kernel_launch(void* const* d_in, const int* in_sizes, int n_in,
                              void* d_out, int out_size, void* d_ws, size_t ws_size,
                              hipStream_t stream) {
    const float* rois   = (const float*)d_in[1];   // [1,N,4]
    const float* gts    = (const float*)d_in[2];   // [1,M,4]
    const int*   labels = (const int*)  d_in[3];   // [1,M]
    int N = in_sizes[1] / 4;
    int M = in_sizes[2] / 4;

    char* ws = (char*)d_ws;
    int*     grpPos = (int*)    (ws + WS_GRPPOS);
    int*     grpNeg = (int*)    (ws + WS_GRPNEG);
    int16_t* bestgt = (int16_t*)(ws + WS_BESTGT);
    uint8_t* key    = (uint8_t*)(ws + WS_KEY);

    int nblk    = (N + 127) / 128;
    int ngroups = (N + 63) / 64;

    iou_kernel<<<nblk, 256, 0, stream>>>(rois, gts, N, M, key, bestgt, grpPos, grpNeg);

    float* outD = (float*)d_out;          // [1,256,4]
    float* outH = outD + RPI * 4;         // [1,256,91]
    finish_kernel<<<1, 1024, 0, stream>>>(rois, gts, labels, key, bestgt,
                                          grpPos, grpNeg, outD, outH, N, ngroups);
}